// Round 8
// baseline (1187.764 us; speedup 1.0000x reference)
//
#include <hip/hip_runtime.h>
#include <stdint.h>

#define NN_NODE 50000
#define NN_EDGE 800000

typedef _Float16 f16;
typedef _Float16 f16x2 __attribute__((ext_vector_type(2)));
typedef _Float16 f16x4 __attribute__((ext_vector_type(4)));
typedef _Float16 f16x8 __attribute__((ext_vector_type(8)));
typedef float f32x4 __attribute__((ext_vector_type(4)));

// ---- workspace layout ----
#define WT_MW0   0        // [256][32]  (K=10 padded to 32)
#define WT_MW1   8192     // [256][256]
#define WT_MW2   73728    // [128][256]
#define WT_AW0   106496   // [128][128]
#define WT_AW1   122880   // [128][128]
#define WT_VW0   139264   // [256][128]
#define WT_VW1   172032   // [128][256]
#define WT_UW0   204800   // [256][128]
#define WT_UW1   237568   // [256][256]
#define WT_TOTAL 303104

#define V_OFF      606208ull                  // f16 v[E][128]   (receiver-sorted)
#define WL_OFF     205406208ull               // float wlog[E]   (receiver-sorted)
#define CNT_OFF    208606208ull               // int cnt/cursor[N]
#define BASE_OFF   208806208ull               // int base[N]
#define AGGR_OFF   209006208ull               // float aggr[N][128]

// XOR-swizzled LDS addressing: rows of 256 f16 = 32 chunks of 8 f16 (16B).
__device__ __forceinline__ int swz(int row, int col) {
    return row * 256 + ((((col >> 3) ^ (row & 7))) << 3) + (col & 7);
}

__device__ __forceinline__ f16x2 pk2(float a, float b) {
    return __builtin_bit_cast(f16x2, __builtin_amdgcn_cvt_pkrtz(a, b));   // v_cvt_pkrtz_f16_f32
}

// ---- fused MLP layer, 16x16x32 MFMA, swapped operands, NW waves ----
// A = weights W^T[n][k], B = activations from LDS (ds_read_b128).
// D: col=edge=lane&15, row=feature=quad*4+reg.
// bf0: first ct-tile weights, preloaded by the PREVIOUS layer (cross-barrier
// prefetch). wtn/bfn: this layer prefetches the NEXT layer's first tile.
// EPI: 0 = relu -> LDS; 1 = partial dot with dvec (no LDS out, lpart[wave*64+..]);
//      2 = relu -> direct global v-store at spos slot.
template<int K, int N, int NKN, int EPI, int NW>
__device__ __forceinline__ void mlayer(const f16* in, int inoff,
        const f16* __restrict__ wt, const float* __restrict__ bias,
        f16* out, int outoff,
        f16x8* bf0, const f16* __restrict__ wtn, f16x8* bfn,
        const float* __restrict__ dvec, float* lpart,
        f16* __restrict__ vout, const int* sposp, int tid)
{
    const int wave = tid >> 6;
    const int lane = tid & 63;
    const int l15  = lane & 15;
    const int quad = lane >> 4;
    constexpr int NKS = K >> 5;
    constexpr int NCT = N >> 4;
    constexpr int ITC = NCT / NW;   // ct-tiles per wave (1 or 2)

    // activation fragments (compiler may rematerialize per ct — that's fine)
    f16x8 af[4][NKS];
#pragma unroll
    for (int ms = 0; ms < 4; ++ms)
#pragma unroll
        for (int ks = 0; ks < NKS; ++ks)
            af[ms][ks] = *(const f16x8*)(in + swz(ms * 16 + l15, inoff + ks * 32 + quad * 8));

    // cross-barrier prefetch: next layer's first ct-tile weights
    if constexpr (NKN > 0) {
        const f16* wrow = wtn + (size_t)(wave * 16 + l15) * (NKN * 32) + quad * 8;
#pragma unroll
        for (int ks = 0; ks < NKN; ++ks) bfn[ks] = *(const f16x8*)(wrow + ks * 32);
    }

    int   sposv[4];
    float preg[4];
    if constexpr (EPI == 2) {
#pragma unroll
        for (int ms = 0; ms < 4; ++ms) sposv[ms] = sposp[ms * 16 + l15];
    }
    if constexpr (EPI == 1) {
#pragma unroll
        for (int ms = 0; ms < 4; ++ms) preg[ms] = 0.f;
    }

    f16x8 bfl[2][NKS > 0 ? NKS : 1];
#pragma unroll
    for (int ks = 0; ks < NKS; ++ks) bfl[0][ks] = bf0[ks];

#pragma unroll
    for (int i = 0; i < ITC; ++i) {
        const int ct = wave + i * NW;
        if (i + 1 < ITC) {   // in-layer prefetch of next ct tile
            const f16* wrow = wt + (size_t)((ct + NW) * 16 + l15) * K + quad * 8;
#pragma unroll
            for (int ks = 0; ks < NKS; ++ks)
                bfl[(i + 1) & 1][ks] = *(const f16x8*)(wrow + ks * 32);
        }
        const int f0 = ct * 16 + quad * 4;
        const float4 bv = *(const float4*)(bias + f0);
        float4 awv;
        if constexpr (EPI == 1) awv = *(const float4*)(dvec + f0);
#pragma unroll
        for (int ms = 0; ms < 4; ++ms) {
            f32x4 acc = {0.f, 0.f, 0.f, 0.f};
#pragma unroll
            for (int ks = 0; ks < NKS; ++ks)
                acc = __builtin_amdgcn_mfma_f32_16x16x32_f16(bfl[i & 1][ks], af[ms][ks], acc, 0, 0, 0);
            if constexpr (EPI == 1) {
                preg[ms] += fmaxf(acc[0] + bv.x, 0.f) * awv.x
                          + fmaxf(acc[1] + bv.y, 0.f) * awv.y
                          + fmaxf(acc[2] + bv.z, 0.f) * awv.z
                          + fmaxf(acc[3] + bv.w, 0.f) * awv.w;
            } else {
                f16x2 lo = pk2(fmaxf(acc[0] + bv.x, 0.f), fmaxf(acc[1] + bv.y, 0.f));
                f16x2 hi = pk2(fmaxf(acc[2] + bv.z, 0.f), fmaxf(acc[3] + bv.w, 0.f));
                f16x4 o; o[0] = lo[0]; o[1] = lo[1]; o[2] = hi[0]; o[3] = hi[1];
                if constexpr (EPI == 0)
                    *(f16x4*)(out + swz(ms * 16 + l15, outoff + f0)) = o;
                else
                    *(f16x4*)(vout + (size_t)sposv[ms] * 128 + f0) = o;
            }
        }
    }
    if constexpr (EPI == 1) {
#pragma unroll
        for (int ms = 0; ms < 4; ++ms) {
            float r = preg[ms];
            r += __shfl_xor(r, 16);
            r += __shfl_xor(r, 32);
            if (quad == 0) lpart[wave * 64 + ms * 16 + l15] = r;
        }
    }
}

// ---- prep: transpose-convert weights to f16 [N][Kpad] ----
struct WSeg { const float* src; int K, N, Kpad, dstOff; };
struct WSegs { WSeg s[9]; };

__global__ void prep_kernel(WSegs segs, f16* __restrict__ wt) {
    int idx = blockIdx.x * 256 + threadIdx.x;
    if (idx >= WT_TOTAL) return;
    int off = idx;
#pragma unroll
    for (int i = 0; i < 9; ++i) {
        int sz = segs.s[i].N * segs.s[i].Kpad;
        if (off < sz) {
            int n = off / segs.s[i].Kpad;
            int k = off - n * segs.s[i].Kpad;
            f16 val = (f16)0.f;
            if (k < segs.s[i].K) val = (f16)segs.s[i].src[k * segs.s[i].N + n];
            wt[segs.s[i].dstOff + off] = val;
            return;
        }
        off -= sz;
    }
}

// ---- sort step 1: histogram of receivers ----
__global__ void hist_kernel(const int* __restrict__ receivers, int* __restrict__ cnt) {
    int e = blockIdx.x * 256 + threadIdx.x;
    atomicAdd(&cnt[receivers[e]], 1);
}

// ---- sort step 2: exclusive scan ----
__global__ __launch_bounds__(1024) void scan_kernel(int* __restrict__ cnt, int* __restrict__ base) {
    __shared__ int psum[1024];
    const int tid = threadIdx.x;
    const int CH = (NN_NODE + 1023) / 1024;
    const int lo = tid * CH;
    const int hi = min(lo + CH, NN_NODE);
    int s = 0;
    for (int i = lo; i < hi; ++i) s += cnt[i];
    psum[tid] = s;
    __syncthreads();
    for (int d = 1; d < 1024; d <<= 1) {
        int v = (tid >= d) ? psum[tid - d] : 0;
        __syncthreads();
        psum[tid] += v;
        __syncthreads();
    }
    int run = psum[tid] - s;
    for (int i = lo; i < hi; ++i) {
        int c = cnt[i];
        base[i] = run;
        cnt[i] = run;
        run += c;
    }
}

// ---- K1: per-edge encoder + attention logit + value; 64 edges, 8 waves ----
__global__ __launch_bounds__(512, 4) void edge_kernel(
        const float* __restrict__ nodes, const float* __restrict__ edges,
        const int* __restrict__ senders, const int* __restrict__ receivers,
        const f16* __restrict__ wt,
        const float* __restrict__ mb0, const float* __restrict__ mb1, const float* __restrict__ mb2,
        const float* __restrict__ ab0, const float* __restrict__ ab1,
        const float* __restrict__ aw2, const float* __restrict__ ab2,
        const float* __restrict__ vb0, const float* __restrict__ vb1,
        f16* __restrict__ vout, float* __restrict__ wlog, int* __restrict__ cursor)
{
    __shared__ f16 ldsbuf[2 * 64 * 256];   // 64 KB
    __shared__ int spos[64];
    __shared__ float lpart[512];
    f16* bufA = ldsbuf;
    f16* bufB = ldsbuf + 64 * 256;
    const int tid = threadIdx.x;
    const int e0 = blockIdx.x * 64;
    const int wave = tid >> 6;
    const int lane = tid & 63;
    const int l15  = lane & 15;
    const int quad = lane >> 4;

    f16x8 bfA[8], bfB[8];

    // preload L0's first weight tile (cross-barrier prefetch seed)
    {
        const f16* wrow = wt + WT_MW0 + (size_t)(wave * 16 + l15) * 32 + quad * 8;
        bfA[0] = *(const f16x8*)wrow;
    }

    // stage z: chunks 0..3 of each row (cols 0..31). chunk0=[s.xyz,r.xyz,e01],
    // chunk1=[e23,0..], chunk2/3=0. waves 4..7 idle here.
    {
        const int e = tid & 63, c = tid >> 6;
        if (c < 4) {
            f16x8 zv = {(f16)0.f,(f16)0.f,(f16)0.f,(f16)0.f,(f16)0.f,(f16)0.f,(f16)0.f,(f16)0.f};
            if (c == 0) {
                int s = senders[e0 + e];
                int r = receivers[e0 + e];
                const float2 ev = *(const float2*)(edges + (size_t)(e0 + e) * 4);
                zv[0] = (f16)nodes[s * 3 + 0]; zv[1] = (f16)nodes[s * 3 + 1]; zv[2] = (f16)nodes[s * 3 + 2];
                zv[3] = (f16)nodes[r * 3 + 0]; zv[4] = (f16)nodes[r * 3 + 1]; zv[5] = (f16)nodes[r * 3 + 2];
                zv[6] = (f16)ev.x; zv[7] = (f16)ev.y;
            } else if (c == 1) {
                const float2 ev = *(const float2*)(edges + (size_t)(e0 + e) * 4 + 2);
                zv[0] = (f16)ev.x; zv[1] = (f16)ev.y;
            }
            *(f16x8*)(bufA + e * 256 + ((c ^ (e & 7)) << 3)) = zv;
        }
    }
    __syncthreads();

    mlayer< 32, 256, 8, 0, 8>(bufA, 0, wt + WT_MW0, mb0, bufB, 0, bfA, wt + WT_MW1, bfB,
                              nullptr, nullptr, nullptr, nullptr, tid);
    __syncthreads();
    mlayer<256, 256, 8, 0, 8>(bufB, 0, wt + WT_MW1, mb1, bufA, 0, bfB, wt + WT_MW2, bfA,
                              nullptr, nullptr, nullptr, nullptr, tid);
    __syncthreads();
    mlayer<256, 128, 4, 0, 8>(bufA, 0, wt + WT_MW2, mb2, bufB, 0, bfA, wt + WT_AW0, bfB,
                              nullptr, nullptr, nullptr, nullptr, tid);   // q in bufB
    __syncthreads();
    mlayer<128, 128, 4, 0, 8>(bufB, 0, wt + WT_AW0, ab0, bufA, 0, bfB, wt + WT_AW1, bfA,
                              nullptr, nullptr, nullptr, nullptr, tid);   // h0 in bufA
    __syncthreads();
    mlayer<128, 128, 4, 1, 8>(bufA, 0, wt + WT_AW1, ab1, nullptr, 0, bfA, wt + WT_VW0, bfB,
                              aw2, lpart, nullptr, nullptr, tid);         // logit partials
    __syncthreads();

    // finalize logits (wave 0) while other waves run VW0
    if (tid < 64) {
        float wv = ab2[0];
#pragma unroll
        for (int w = 0; w < 8; ++w) wv += lpart[w * 64 + tid];
        int r = receivers[e0 + tid];
        int pos = atomicAdd(&cursor[r], 1);
        spos[tid] = pos;
        wlog[pos] = wv;
    }
    mlayer<128, 256, 8, 0, 8>(bufB, 0, wt + WT_VW0, vb0, bufA, 0, bfB, wt + WT_VW1, bfA,
                              nullptr, nullptr, nullptr, nullptr, tid);
    __syncthreads();
    mlayer<256, 128, 0, 2, 8>(bufA, 0, wt + WT_VW1, vb1, nullptr, 0, bfA, nullptr, nullptr,
                              nullptr, nullptr, vout, spos, tid);         // v direct to global
}

// ---- K2: per-node segmented softmax + weighted aggregation (1 wave / node) ----
__global__ __launch_bounds__(256) void aggregate_kernel(
        const float* __restrict__ wlog, const f16* __restrict__ v,
        const int* __restrict__ base, float* __restrict__ aggr)
{
    const int tid = threadIdx.x;
    const int n = blockIdx.x * 4 + (tid >> 6);
    const int lane = tid & 63;
    int st = base[n];
    int en = (n == NN_NODE - 1) ? NN_EDGE : base[n + 1];
    // replay-robustness clamps (profiling passes may see stale base)
    st = max(0, min(st, NN_EDGE));
    en = max(st, min(en, NN_EDGE));

    float mx = -1e9f;
    for (int i = st + lane; i < en; i += 64) mx = fmaxf(mx, wlog[i]);
#pragma unroll
    for (int d = 1; d < 64; d <<= 1) mx = fmaxf(mx, __shfl_xor(mx, d));

    float sm = 0.f;
    for (int i = st + lane; i < en; i += 64) sm += __expf(wlog[i] - mx);
#pragma unroll
    for (int d = 1; d < 64; d <<= 1) sm += __shfl_xor(sm, d);
    const float inv = 1.f / (sm + 1e-12f);

    float acc0 = 0.f, acc1 = 0.f;
    const f16* vp = v + (size_t)st * 128 + lane * 2;
    for (int i = st; i < en; ++i, vp += 128) {
        float attn = __expf(wlog[i] - mx) * inv;
        f16x2 vv = *(const f16x2*)vp;
        acc0 += attn * (float)vv[0];
        acc1 += attn * (float)vv[1];
    }
    float2 o; o.x = acc0; o.y = acc1;
    *(float2*)(aggr + (size_t)n * 128 + lane * 2) = o;
}

// ---- K3: node decoder (64-node tiles, 8 waves, uw2 dot fused into UW1) ----
__global__ __launch_bounds__(512, 4) void node_kernel(
        const float* __restrict__ aggr, const f16* __restrict__ wt,
        const float* __restrict__ ub0, const float* __restrict__ ub1,
        const float* __restrict__ uw2, const float* __restrict__ ub2,
        float* __restrict__ out)
{
    __shared__ f16 ldsbuf[2 * 64 * 256];
    __shared__ float lpart[512];
    f16* bufA = ldsbuf;
    f16* bufB = ldsbuf + 64 * 256;
    const int tid = threadIdx.x;
    const int n0 = blockIdx.x * 64;
    const int wave = tid >> 6;
    const int lane = tid & 63;
    const int l15  = lane & 15;
    const int quad = lane >> 4;

    f16x8 bfA[8], bfB[8];
    {
        const f16* wrow = wt + WT_UW0 + (size_t)(wave * 16 + l15) * 128 + quad * 8;
#pragma unroll
        for (int ks = 0; ks < 4; ++ks) bfA[ks] = *(const f16x8*)(wrow + ks * 32);
    }

    // stage aggr rows (128 f32 -> f16) into bufA cols 0..127
    {
        int row = tid >> 3, j = tid & 7;   // 64 rows x 8 parts of 16 cols
        int n = n0 + row;
        f16x8 p0, p1;
        if (n < NN_NODE) {
            const float4* src = (const float4*)(aggr + (size_t)n * 128 + j * 16);
            float4 a = src[0], b = src[1], c = src[2], d = src[3];
            f16x2 q0 = pk2(a.x, a.y), q1 = pk2(a.z, a.w), q2 = pk2(b.x, b.y), q3 = pk2(b.z, b.w);
            f16x2 q4 = pk2(c.x, c.y), q5 = pk2(c.z, c.w), q6 = pk2(d.x, d.y), q7 = pk2(d.z, d.w);
            p0[0]=q0[0]; p0[1]=q0[1]; p0[2]=q1[0]; p0[3]=q1[1]; p0[4]=q2[0]; p0[5]=q2[1]; p0[6]=q3[0]; p0[7]=q3[1];
            p1[0]=q4[0]; p1[1]=q4[1]; p1[2]=q5[0]; p1[3]=q5[1]; p1[4]=q6[0]; p1[5]=q6[1]; p1[6]=q7[0]; p1[7]=q7[1];
        } else {
            p0 = (f16x8)(f16)0.f; p1 = (f16x8)(f16)0.f;
        }
        *(f16x8*)(bufA + row * 256 + (((2 * j) ^ (row & 7)) << 3)) = p0;
        *(f16x8*)(bufA + row * 256 + (((2 * j + 1) ^ (row & 7)) << 3)) = p1;
    }
    __syncthreads();

    mlayer<128, 256, 8, 0, 8>(bufA, 0, wt + WT_UW0, ub0, bufB, 0, bfA, wt + WT_UW1, bfB,
                              nullptr, nullptr, nullptr, nullptr, tid);
    __syncthreads();
    mlayer<256, 256, 0, 1, 8>(bufB, 0, wt + WT_UW1, ub1, nullptr, 0, bfB, nullptr, nullptr,
                              uw2, lpart, nullptr, nullptr, tid);
    __syncthreads();
    if (tid < 64) {
        float sum = ub2[0];
#pragma unroll
        for (int w = 0; w < 8; ++w) sum += lpart[w * 64 + tid];
        int n = n0 + tid;
        if (n < NN_NODE) out[n] = sum;
    }
}

extern "C" void kernel_launch(void* const* d_in, const int* in_sizes, int n_in,
                              void* d_out, int out_size, void* d_ws, size_t ws_size,
                              hipStream_t stream)
{
    const float* nodes     = (const float*)d_in[0];
    const float* edges     = (const float*)d_in[1];
    const int*   senders   = (const int*)d_in[2];
    const int*   receivers = (const int*)d_in[3];
    const float* mw0 = (const float*)d_in[4];  const float* mb0 = (const float*)d_in[5];
    const float* mw1 = (const float*)d_in[6];  const float* mb1 = (const float*)d_in[7];
    const float* mw2 = (const float*)d_in[8];  const float* mb2 = (const float*)d_in[9];
    const float* aw0 = (const float*)d_in[10]; const float* ab0 = (const float*)d_in[11];
    const float* aw1 = (const float*)d_in[12]; const float* ab1 = (const float*)d_in[13];
    const float* aw2 = (const float*)d_in[14]; const float* ab2 = (const float*)d_in[15];
    const float* vw0 = (const float*)d_in[16]; const float* vb0 = (const float*)d_in[17];
    const float* vw1 = (const float*)d_in[18]; const float* vb1 = (const float*)d_in[19];
    const float* uw0 = (const float*)d_in[20]; const float* ub0 = (const float*)d_in[21];
    const float* uw1 = (const float*)d_in[22]; const float* ub1 = (const float*)d_in[23];
    const float* uw2 = (const float*)d_in[24]; const float* ub2 = (const float*)d_in[25];

    char* ws = (char*)d_ws;
    f16*   wt   = (f16*)ws;
    f16*   vbuf = (f16*)(ws + V_OFF);
    float* wlog = (float*)(ws + WL_OFF);
    int*   cnt  = (int*)(ws + CNT_OFF);
    int*   base = (int*)(ws + BASE_OFF);
    float* aggr = (float*)(ws + AGGR_OFF);
    float* out  = (float*)d_out;

    (void)hipMemsetAsync(cnt, 0, NN_NODE * sizeof(int), stream);

    WSegs segs = {{
        { mw0,  10, 256,  32, WT_MW0 },
        { mw1, 256, 256, 256, WT_MW1 },
        { mw2, 256, 128, 256, WT_MW2 },
        { aw0, 128, 128, 128, WT_AW0 },
        { aw1, 128, 128, 128, WT_AW1 },
        { vw0, 128, 256, 128, WT_VW0 },
        { vw1, 256, 128, 256, WT_VW1 },
        { uw0, 128, 256, 128, WT_UW0 },
        { uw1, 256, 256, 256, WT_UW1 },
    }};
    prep_kernel<<<(WT_TOTAL + 255) / 256, 256, 0, stream>>>(segs, wt);

    hist_kernel<<<NN_EDGE / 256, 256, 0, stream>>>(receivers, cnt);
    scan_kernel<<<1, 1024, 0, stream>>>(cnt, base);

    edge_kernel<<<NN_EDGE / 64, 512, 0, stream>>>(nodes, edges, senders, receivers, wt,
        mb0, mb1, mb2, ab0, ab1, aw2, ab2, vb0, vb1, vbuf, wlog, cnt);

    aggregate_kernel<<<NN_NODE / 4, 256, 0, stream>>>(wlog, vbuf, base, aggr);

    node_kernel<<<(NN_NODE + 63) / 64, 512, 0, stream>>>(aggr, wt, ub0, ub1, uw2, ub2, out);
}

// Round 9
// 1005.088 us; speedup vs baseline: 1.1818x; 1.1818x over previous
//
#include <hip/hip_runtime.h>
#include <stdint.h>

#define NN_NODE 50000
#define NN_EDGE 800000

typedef _Float16 f16;
typedef _Float16 f16x2 __attribute__((ext_vector_type(2)));
typedef _Float16 f16x4 __attribute__((ext_vector_type(4)));
typedef _Float16 f16x8 __attribute__((ext_vector_type(8)));
typedef float f32x4 __attribute__((ext_vector_type(4)));

// Pin a value into VGPRs: asm-defined values cannot be rematerialized, so the
// compiler must keep the loaded fragment live instead of re-reading LDS.
#define KEEP(x) asm volatile("" : "+v"(x))

// ---- workspace layout ----
#define WT_MW0   0        // [256][32]  (K=10 padded to 32)
#define WT_MW1   8192     // [256][256]
#define WT_MW2   73728    // [128][256]
#define WT_AW0   106496   // [128][128]
#define WT_AW1   122880   // [128][128]
#define WT_VW0   139264   // [256][128]
#define WT_VW1   172032   // [128][256]
#define WT_UW0   204800   // [256][128]
#define WT_UW1   237568   // [256][256]
#define WT_TOTAL 303104

#define V_OFF      606208ull                  // f16 v[E][128]   (receiver-sorted)
#define WL_OFF     205406208ull               // float wlog[E]   (receiver-sorted)
#define CNT_OFF    208606208ull               // int cnt/cursor[N]
#define BASE_OFF   208806208ull               // int base[N]
#define AGGR_OFF   209006208ull               // float aggr[N][128]

// XOR-swizzled LDS addressing: rows of 256 f16 = 32 chunks of 8 f16 (16B).
__device__ __forceinline__ int swz(int row, int col) {
    return row * 256 + ((((col >> 3) ^ (row & 7))) << 3) + (col & 7);
}

__device__ __forceinline__ f16x2 pk2(float a, float b) {
    return __builtin_bit_cast(f16x2, __builtin_amdgcn_cvt_pkrtz(a, b));   // v_cvt_pkrtz_f16_f32
}

// ---- fused MLP layer, 16x16x32 MFMA, swapped operands, NW=4 waves ----
// A = weights W^T[n][k] (global/L2), B = activations from LDS (ds_read_b128).
// D: col=edge=lane&15, row=feature=quad*4+reg.
// af fragments loaded ONCE per layer and pinned in VGPRs via KEEP (no remat):
// LDS reads/block drop ~2.7x vs compiler's per-ct rematerialization.
// bf0: first ct-tile weights preloaded by the PREVIOUS layer (cross-barrier
// prefetch). wtn/bfn: this layer prefetches the NEXT layer's first tile.
// EPI: 0 = relu -> LDS; 1 = partial dot with dvec -> lpart; 2 = relu -> global v.
template<int K, int N, int NKN, int EPI, int NW>
__device__ __forceinline__ void mlayer(const f16* in, int inoff,
        const f16* __restrict__ wt, const float* __restrict__ bias,
        f16* out, int outoff,
        f16x8* bf0, const f16* __restrict__ wtn, f16x8* bfn,
        const float* __restrict__ dvec, float* lpart,
        f16* __restrict__ vout, const int* sposp, int tid)
{
    const int wave = tid >> 6;
    const int lane = tid & 63;
    const int l15  = lane & 15;
    const int quad = lane >> 4;
    constexpr int NKS = K >> 5;
    constexpr int NCT = N >> 4;
    constexpr int ITC = NCT / NW;   // ct-tiles per wave

    // activation fragments: load once, pin in registers
    f16x8 af[4][NKS];
#pragma unroll
    for (int ms = 0; ms < 4; ++ms)
#pragma unroll
        for (int ks = 0; ks < NKS; ++ks) {
            af[ms][ks] = *(const f16x8*)(in + swz(ms * 16 + l15, inoff + ks * 32 + quad * 8));
            KEEP(af[ms][ks]);
        }

    // cross-barrier prefetch: next layer's first ct-tile weights
    if constexpr (NKN > 0) {
        const f16* wrow = wtn + (size_t)(wave * 16 + l15) * (NKN * 32) + quad * 8;
#pragma unroll
        for (int ks = 0; ks < NKN; ++ks) bfn[ks] = *(const f16x8*)(wrow + ks * 32);
    }

    int   sposv[4];
    float preg[4];
    if constexpr (EPI == 2) {
#pragma unroll
        for (int ms = 0; ms < 4; ++ms) sposv[ms] = sposp[ms * 16 + l15];
    }
    if constexpr (EPI == 1) {
#pragma unroll
        for (int ms = 0; ms < 4; ++ms) preg[ms] = 0.f;
    }

    f16x8 bfl[2][NKS > 0 ? NKS : 1];
#pragma unroll
    for (int ks = 0; ks < NKS; ++ks) bfl[0][ks] = bf0[ks];

#pragma unroll
    for (int i = 0; i < ITC; ++i) {
        const int ct = wave + i * NW;
        if (i + 1 < ITC) {   // in-layer prefetch of next ct tile
            const f16* wrow = wt + (size_t)((ct + NW) * 16 + l15) * K + quad * 8;
#pragma unroll
            for (int ks = 0; ks < NKS; ++ks)
                bfl[(i + 1) & 1][ks] = *(const f16x8*)(wrow + ks * 32);
        }
        const int f0 = ct * 16 + quad * 4;
        const float4 bv = *(const float4*)(bias + f0);
        float4 awv;
        if constexpr (EPI == 1) awv = *(const float4*)(dvec + f0);
#pragma unroll
        for (int ms = 0; ms < 4; ++ms) {
            f32x4 acc = {0.f, 0.f, 0.f, 0.f};
#pragma unroll
            for (int ks = 0; ks < NKS; ++ks)
                acc = __builtin_amdgcn_mfma_f32_16x16x32_f16(bfl[i & 1][ks], af[ms][ks], acc, 0, 0, 0);
            if constexpr (EPI == 1) {
                preg[ms] += fmaxf(acc[0] + bv.x, 0.f) * awv.x
                          + fmaxf(acc[1] + bv.y, 0.f) * awv.y
                          + fmaxf(acc[2] + bv.z, 0.f) * awv.z
                          + fmaxf(acc[3] + bv.w, 0.f) * awv.w;
            } else {
                f16x2 lo = pk2(fmaxf(acc[0] + bv.x, 0.f), fmaxf(acc[1] + bv.y, 0.f));
                f16x2 hi = pk2(fmaxf(acc[2] + bv.z, 0.f), fmaxf(acc[3] + bv.w, 0.f));
                f16x4 o; o[0] = lo[0]; o[1] = lo[1]; o[2] = hi[0]; o[3] = hi[1];
                if constexpr (EPI == 0)
                    *(f16x4*)(out + swz(ms * 16 + l15, outoff + f0)) = o;
                else
                    *(f16x4*)(vout + (size_t)sposv[ms] * 128 + f0) = o;
            }
        }
    }
    if constexpr (EPI == 1) {
#pragma unroll
        for (int ms = 0; ms < 4; ++ms) {
            float r = preg[ms];
            r += __shfl_xor(r, 16);
            r += __shfl_xor(r, 32);
            if (quad == 0) lpart[wave * 64 + ms * 16 + l15] = r;
        }
    }
}

// ---- prep: transpose-convert weights to f16 [N][Kpad] ----
struct WSeg { const float* src; int K, N, Kpad, dstOff; };
struct WSegs { WSeg s[9]; };

__global__ void prep_kernel(WSegs segs, f16* __restrict__ wt) {
    int idx = blockIdx.x * 256 + threadIdx.x;
    if (idx >= WT_TOTAL) return;
    int off = idx;
#pragma unroll
    for (int i = 0; i < 9; ++i) {
        int sz = segs.s[i].N * segs.s[i].Kpad;
        if (off < sz) {
            int n = off / segs.s[i].Kpad;
            int k = off - n * segs.s[i].Kpad;
            f16 val = (f16)0.f;
            if (k < segs.s[i].K) val = (f16)segs.s[i].src[k * segs.s[i].N + n];
            wt[segs.s[i].dstOff + off] = val;
            return;
        }
        off -= sz;
    }
}

// ---- sort step 1: histogram of receivers ----
__global__ void hist_kernel(const int* __restrict__ receivers, int* __restrict__ cnt) {
    int e = blockIdx.x * 256 + threadIdx.x;
    atomicAdd(&cnt[receivers[e]], 1);
}

// ---- sort step 2: exclusive scan ----
__global__ __launch_bounds__(1024) void scan_kernel(int* __restrict__ cnt, int* __restrict__ base) {
    __shared__ int psum[1024];
    const int tid = threadIdx.x;
    const int CH = (NN_NODE + 1023) / 1024;
    const int lo = tid * CH;
    const int hi = min(lo + CH, NN_NODE);
    int s = 0;
    for (int i = lo; i < hi; ++i) s += cnt[i];
    psum[tid] = s;
    __syncthreads();
    for (int d = 1; d < 1024; d <<= 1) {
        int v = (tid >= d) ? psum[tid - d] : 0;
        __syncthreads();
        psum[tid] += v;
        __syncthreads();
    }
    int run = psum[tid] - s;
    for (int i = lo; i < hi; ++i) {
        int c = cnt[i];
        base[i] = run;
        cnt[i] = run;
        run += c;
    }
}

// ---- K1: per-edge encoder + attention logit + value; 64 edges, 4 waves ----
__global__ __launch_bounds__(256, 2) void edge_kernel(
        const float* __restrict__ nodes, const float* __restrict__ edges,
        const int* __restrict__ senders, const int* __restrict__ receivers,
        const f16* __restrict__ wt,
        const float* __restrict__ mb0, const float* __restrict__ mb1, const float* __restrict__ mb2,
        const float* __restrict__ ab0, const float* __restrict__ ab1,
        const float* __restrict__ aw2, const float* __restrict__ ab2,
        const float* __restrict__ vb0, const float* __restrict__ vb1,
        f16* __restrict__ vout, float* __restrict__ wlog, int* __restrict__ cursor)
{
    __shared__ f16 ldsbuf[2 * 64 * 256];   // 64 KB
    __shared__ int spos[64];
    __shared__ float lpart[256];
    f16* bufA = ldsbuf;
    f16* bufB = ldsbuf + 64 * 256;
    const int tid = threadIdx.x;
    const int e0 = blockIdx.x * 64;
    const int wave = tid >> 6;
    const int lane = tid & 63;
    const int l15  = lane & 15;
    const int quad = lane >> 4;

    f16x8 bfA[8], bfB[8];

    // preload L0's first weight tile (cross-barrier prefetch seed)
    {
        const f16* wrow = wt + WT_MW0 + (size_t)(wave * 16 + l15) * 32 + quad * 8;
        bfA[0] = *(const f16x8*)wrow;
    }

    // stage z: chunks 0..3 of each row (cols 0..31). chunk0=[s.xyz,r.xyz,e01],
    // chunk1=[e23,0..], chunk2/3=0.
    {
        const int e = tid & 63, c = tid >> 6;
        f16x8 zv = {(f16)0.f,(f16)0.f,(f16)0.f,(f16)0.f,(f16)0.f,(f16)0.f,(f16)0.f,(f16)0.f};
        if (c == 0) {
            int s = senders[e0 + e];
            int r = receivers[e0 + e];
            const float2 ev = *(const float2*)(edges + (size_t)(e0 + e) * 4);
            zv[0] = (f16)nodes[s * 3 + 0]; zv[1] = (f16)nodes[s * 3 + 1]; zv[2] = (f16)nodes[s * 3 + 2];
            zv[3] = (f16)nodes[r * 3 + 0]; zv[4] = (f16)nodes[r * 3 + 1]; zv[5] = (f16)nodes[r * 3 + 2];
            zv[6] = (f16)ev.x; zv[7] = (f16)ev.y;
        } else if (c == 1) {
            const float2 ev = *(const float2*)(edges + (size_t)(e0 + e) * 4 + 2);
            zv[0] = (f16)ev.x; zv[1] = (f16)ev.y;
        }
        *(f16x8*)(bufA + e * 256 + ((c ^ (e & 7)) << 3)) = zv;
    }
    __syncthreads();

    mlayer< 32, 256, 8, 0, 4>(bufA, 0, wt + WT_MW0, mb0, bufB, 0, bfA, wt + WT_MW1, bfB,
                              nullptr, nullptr, nullptr, nullptr, tid);
    __syncthreads();
    mlayer<256, 256, 8, 0, 4>(bufB, 0, wt + WT_MW1, mb1, bufA, 0, bfB, wt + WT_MW2, bfA,
                              nullptr, nullptr, nullptr, nullptr, tid);
    __syncthreads();
    mlayer<256, 128, 4, 0, 4>(bufA, 0, wt + WT_MW2, mb2, bufB, 0, bfA, wt + WT_AW0, bfB,
                              nullptr, nullptr, nullptr, nullptr, tid);   // q in bufB
    __syncthreads();
    mlayer<128, 128, 4, 0, 4>(bufB, 0, wt + WT_AW0, ab0, bufA, 0, bfB, wt + WT_AW1, bfA,
                              nullptr, nullptr, nullptr, nullptr, tid);   // h0 in bufA
    __syncthreads();
    mlayer<128, 128, 4, 1, 4>(bufA, 0, wt + WT_AW1, ab1, nullptr, 0, bfA, wt + WT_VW0, bfB,
                              aw2, lpart, nullptr, nullptr, tid);         // logit partials
    __syncthreads();

    // finalize logits (wave 0) while other waves run VW0
    if (tid < 64) {
        float wv = ab2[0];
#pragma unroll
        for (int w = 0; w < 4; ++w) wv += lpart[w * 64 + tid];
        int r = receivers[e0 + tid];
        int pos = atomicAdd(&cursor[r], 1);
        spos[tid] = pos;
        wlog[pos] = wv;
    }
    mlayer<128, 256, 8, 0, 4>(bufB, 0, wt + WT_VW0, vb0, bufA, 0, bfB, wt + WT_VW1, bfA,
                              nullptr, nullptr, nullptr, nullptr, tid);
    __syncthreads();
    mlayer<256, 128, 0, 2, 4>(bufA, 0, wt + WT_VW1, vb1, nullptr, 0, bfA, nullptr, nullptr,
                              nullptr, nullptr, vout, spos, tid);         // v direct to global
}

// ---- K2: per-node segmented softmax + weighted aggregation (1 wave / node) ----
__global__ __launch_bounds__(256) void aggregate_kernel(
        const float* __restrict__ wlog, const f16* __restrict__ v,
        const int* __restrict__ base, float* __restrict__ aggr)
{
    const int tid = threadIdx.x;
    const int n = blockIdx.x * 4 + (tid >> 6);
    const int lane = tid & 63;
    int st = base[n];
    int en = (n == NN_NODE - 1) ? NN_EDGE : base[n + 1];
    // replay-robustness clamps (profiling passes may see stale base)
    st = max(0, min(st, NN_EDGE));
    en = max(st, min(en, NN_EDGE));

    float mx = -1e9f;
    for (int i = st + lane; i < en; i += 64) mx = fmaxf(mx, wlog[i]);
#pragma unroll
    for (int d = 1; d < 64; d <<= 1) mx = fmaxf(mx, __shfl_xor(mx, d));

    float sm = 0.f;
    for (int i = st + lane; i < en; i += 64) sm += __expf(wlog[i] - mx);
#pragma unroll
    for (int d = 1; d < 64; d <<= 1) sm += __shfl_xor(sm, d);
    const float inv = 1.f / (sm + 1e-12f);

    float acc0 = 0.f, acc1 = 0.f;
    const f16* vp = v + (size_t)st * 128 + lane * 2;
    for (int i = st; i < en; ++i, vp += 128) {
        float attn = __expf(wlog[i] - mx) * inv;
        f16x2 vv = *(const f16x2*)vp;
        acc0 += attn * (float)vv[0];
        acc1 += attn * (float)vv[1];
    }
    float2 o; o.x = acc0; o.y = acc1;
    *(float2*)(aggr + (size_t)n * 128 + lane * 2) = o;
}

// ---- K3: node decoder (64-node tiles, 4 waves, uw2 dot fused into UW1) ----
__global__ __launch_bounds__(256, 2) void node_kernel(
        const float* __restrict__ aggr, const f16* __restrict__ wt,
        const float* __restrict__ ub0, const float* __restrict__ ub1,
        const float* __restrict__ uw2, const float* __restrict__ ub2,
        float* __restrict__ out)
{
    __shared__ f16 ldsbuf[2 * 64 * 256];
    __shared__ float lpart[256];
    f16* bufA = ldsbuf;
    f16* bufB = ldsbuf + 64 * 256;
    const int tid = threadIdx.x;
    const int n0 = blockIdx.x * 64;
    const int wave = tid >> 6;
    const int lane = tid & 63;
    const int l15  = lane & 15;
    const int quad = lane >> 4;

    f16x8 bfA[8], bfB[8];
    {
        const f16* wrow = wt + WT_UW0 + (size_t)(wave * 16 + l15) * 128 + quad * 8;
#pragma unroll
        for (int ks = 0; ks < 4; ++ks) bfA[ks] = *(const f16x8*)(wrow + ks * 32);
    }

    // stage aggr rows (128 f32 -> f16) into bufA cols 0..127 (b128 writes)
    {
        int row = tid >> 2, j = tid & 3;   // 64 rows x 4 parts of 32 cols
        int n = n0 + row;
#pragma unroll
        for (int c2 = 0; c2 < 4; ++c2) {
            f16x8 p;
            if (n < NN_NODE) {
                const float4* src = (const float4*)(aggr + (size_t)n * 128 + j * 32 + c2 * 8);
                float4 a = src[0], b = src[1];
                f16x2 q0 = pk2(a.x, a.y), q1 = pk2(a.z, a.w);
                f16x2 q2 = pk2(b.x, b.y), q3 = pk2(b.z, b.w);
                p[0]=q0[0]; p[1]=q0[1]; p[2]=q1[0]; p[3]=q1[1];
                p[4]=q2[0]; p[5]=q2[1]; p[6]=q3[0]; p[7]=q3[1];
            } else {
                p = (f16x8)(f16)0.f;
            }
            int chunk = j * 4 + c2;
            *(f16x8*)(bufA + row * 256 + ((chunk ^ (row & 7)) << 3)) = p;
        }
    }
    __syncthreads();

    mlayer<128, 256, 8, 0, 4>(bufA, 0, wt + WT_UW0, ub0, bufB, 0, bfA, wt + WT_UW1, bfB,
                              nullptr, nullptr, nullptr, nullptr, tid);
    __syncthreads();
    mlayer<256, 256, 0, 1, 4>(bufB, 0, wt + WT_UW1, ub1, nullptr, 0, bfB, nullptr, nullptr,
                              uw2, lpart, nullptr, nullptr, tid);
    __syncthreads();
    if (tid < 64) {
        float sum = ub2[0];
#pragma unroll
        for (int w = 0; w < 4; ++w) sum += lpart[w * 64 + tid];
        int n = n0 + tid;
        if (n < NN_NODE) out[n] = sum;
    }
}

extern "C" void kernel_launch(void* const* d_in, const int* in_sizes, int n_in,
                              void* d_out, int out_size, void* d_ws, size_t ws_size,
                              hipStream_t stream)
{
    const float* nodes     = (const float*)d_in[0];
    const float* edges     = (const float*)d_in[1];
    const int*   senders   = (const int*)d_in[2];
    const int*   receivers = (const int*)d_in[3];
    const float* mw0 = (const float*)d_in[4];  const float* mb0 = (const float*)d_in[5];
    const float* mw1 = (const float*)d_in[6];  const float* mb1 = (const float*)d_in[7];
    const float* mw2 = (const float*)d_in[8];  const float* mb2 = (const float*)d_in[9];
    const float* aw0 = (const float*)d_in[10]; const float* ab0 = (const float*)d_in[11];
    const float* aw1 = (const float*)d_in[12]; const float* ab1 = (const float*)d_in[13];
    const float* aw2 = (const float*)d_in[14]; const float* ab2 = (const float*)d_in[15];
    const float* vw0 = (const float*)d_in[16]; const float* vb0 = (const float*)d_in[17];
    const float* vw1 = (const float*)d_in[18]; const float* vb1 = (const float*)d_in[19];
    const float* uw0 = (const float*)d_in[20]; const float* ub0 = (const float*)d_in[21];
    const float* uw1 = (const float*)d_in[22]; const float* ub1 = (const float*)d_in[23];
    const float* uw2 = (const float*)d_in[24]; const float* ub2 = (const float*)d_in[25];

    char* ws = (char*)d_ws;
    f16*   wt   = (f16*)ws;
    f16*   vbuf = (f16*)(ws + V_OFF);
    float* wlog = (float*)(ws + WL_OFF);
    int*   cnt  = (int*)(ws + CNT_OFF);
    int*   base = (int*)(ws + BASE_OFF);
    float* aggr = (float*)(ws + AGGR_OFF);
    float* out  = (float*)d_out;

    (void)hipMemsetAsync(cnt, 0, NN_NODE * sizeof(int), stream);

    WSegs segs = {{
        { mw0,  10, 256,  32, WT_MW0 },
        { mw1, 256, 256, 256, WT_MW1 },
        { mw2, 256, 128, 256, WT_MW2 },
        { aw0, 128, 128, 128, WT_AW0 },
        { aw1, 128, 128, 128, WT_AW1 },
        { vw0, 128, 256, 128, WT_VW0 },
        { vw1, 256, 128, 256, WT_VW1 },
        { uw0, 128, 256, 128, WT_UW0 },
        { uw1, 256, 256, 256, WT_UW1 },
    }};
    prep_kernel<<<(WT_TOTAL + 255) / 256, 256, 0, stream>>>(segs, wt);

    hist_kernel<<<NN_EDGE / 256, 256, 0, stream>>>(receivers, cnt);
    scan_kernel<<<1, 1024, 0, stream>>>(cnt, base);

    edge_kernel<<<NN_EDGE / 64, 256, 0, stream>>>(nodes, edges, senders, receivers, wt,
        mb0, mb1, mb2, ab0, ab1, aw2, ab2, vb0, vb1, vbuf, wlog, cnt);

    aggregate_kernel<<<NN_NODE / 4, 256, 0, stream>>>(wlog, vbuf, base, aggr);

    node_kernel<<<(NN_NODE + 63) / 64, 256, 0, stream>>>(aggr, wt, ub0, ub1, uw2, ub2, out);
}